// Round 3
// baseline (741.417 us; speedup 1.0000x reference)
//
#include <hip/hip_runtime.h>
#include <hip/hip_bf16.h>
#include <math.h>

#define T_TOK 2048
#define DM    1024
#define DF    4096
#define NE    8
#define BM    128
#define BN    128
#define BK    32
#define CH    132   // rows per k-chunk in LDS (16B units); 132 => 2-way-max bank aliasing

typedef __attribute__((ext_vector_type(8))) short          bf16x8;
typedef __attribute__((ext_vector_type(8))) unsigned short ushort8;
typedef __attribute__((ext_vector_type(4))) float          f32x4;

__device__ __forceinline__ unsigned short f2bf(float f) {
  unsigned u = __builtin_bit_cast(unsigned, f);
  unsigned r = u + 0x7fffu + ((u >> 16) & 1u);   // RNE
  return (unsigned short)(r >> 16);
}

// Raw barrier: orders LDS (lgkmcnt(0)) but leaves global prefetch loads in flight
// (no vmcnt drain — this is the point; __syncthreads() would emit vmcnt(0)).
__device__ __forceinline__ void wg_barrier() {
  asm volatile("s_waitcnt lgkmcnt(0)\n\ts_barrier" ::: "memory");
}

// ---------------- x f32 -> bf16 ----------------
__global__ void convert_x_kernel(const float* __restrict__ x, unsigned short* __restrict__ xb) {
  int i = blockIdx.x * blockDim.x + threadIdx.x;
  const float* src = x + (size_t)i * 8;
  float4 a = *(const float4*)(src);
  float4 b = *(const float4*)(src + 4);
  ushort8 v;
  v[0] = f2bf(a.x); v[1] = f2bf(a.y); v[2] = f2bf(a.z); v[3] = f2bf(a.w);
  v[4] = f2bf(b.x); v[5] = f2bf(b.y); v[6] = f2bf(b.z); v[7] = f2bf(b.w);
  *(ushort8*)(xb + (size_t)i * 8) = v;
}

// ---------------- weight convert + transpose: W[E][K][N] f32 -> Wt[E][N][K] bf16 ----------------
template<int K, int N>
__global__ __launch_bounds__(256) void transpose_convert(
    const float* __restrict__ W, unsigned short* __restrict__ Wt)
{
  const int e  = blockIdx.z;
  const int k0 = blockIdx.y * 32;
  const int n0 = blockIdx.x * 128;
  const float* Wp = W + (size_t)e * K * N;
  unsigned short* Wo = Wt + (size_t)e * N * K;
  __shared__ float Ls[32][132];                    // pitch 132: 16B-aligned rows, low conflicts
  const int tid = threadIdx.x;
  {
    const int kl = tid >> 5;
    const int nl = (tid & 31) * 4;
#pragma unroll
    for (int p = 0; p < 4; p++) {
      const int k = kl + p * 8;
      float4 v = *(const float4*)(Wp + (size_t)(k0 + k) * N + n0 + nl);
      *(float4*)&Ls[k][nl] = v;                    // ds_write_b128, conflict-free
    }
  }
  __syncthreads();
  {
    const int n  = tid & 127;
    const int c0 = tid >> 7;
#pragma unroll
    for (int p = 0; p < 2; p++) {
      const int c = c0 + p * 2;
      ushort8 o;
#pragma unroll
      for (int j = 0; j < 8; j++) o[j] = f2bf(Ls[c * 8 + j][n]);
      *(ushort8*)(Wo + (size_t)(n0 + n) * K + k0 + c * 8) = o;
    }
  }
}

// ---------------- gating: one wave per token ----------------
__global__ __launch_bounds__(256) void gating_kernel(
    const float* __restrict__ x, const float* __restrict__ wg, const float* __restrict__ bg,
    int* __restrict__ cnt, int* __restrict__ perm, float* __restrict__ pw)
{
  int wid  = (blockIdx.x * blockDim.x + threadIdx.x) >> 6;
  int lane = threadIdx.x & 63;
  if (wid >= T_TOK) return;
  const float* xr = x + (size_t)wid * DM;

  float acc[NE];
#pragma unroll
  for (int e = 0; e < NE; e++) acc[e] = 0.f;
  for (int d = lane; d < DM; d += 64) {
    float xv = xr[d];
    const float* wr = wg + (size_t)d * NE;
#pragma unroll
    for (int e = 0; e < NE; e++) acc[e] += xv * wr[e];
  }
#pragma unroll
  for (int off = 32; off > 0; off >>= 1) {
#pragma unroll
    for (int e = 0; e < NE; e++) acc[e] += __shfl_xor(acc[e], off, 64);
  }
  if (lane == 0) {
    float v[NE];
#pragma unroll
    for (int e = 0; e < NE; e++) v[e] = acc[e] + bg[e];
    int i0 = 0; float v0 = v[0];
#pragma unroll
    for (int e = 1; e < NE; e++) { if (v[e] > v0) { v0 = v[e]; i0 = e; } }
    int i1 = -1; float v1 = -INFINITY;
#pragma unroll
    for (int e = 0; e < NE; e++) { if (e != i0 && v[e] > v1) { v1 = v[e]; i1 = e; } }
    float e1 = expf(v1 - v0);
    float s  = 1.f + e1;
    float w0 = 1.f / s, w1 = e1 / s;
    int p0 = atomicAdd(&cnt[i0], 1);
    perm[i0 * T_TOK + p0] = wid; pw[i0 * T_TOK + p0] = w0;
    int p1 = atomicAdd(&cnt[i1], 1);
    perm[i1 * T_TOK + p1] = wid; pw[i1 * T_TOK + p1] = w1;
  }
}

// ---------------- pad lists to BM multiple + exclusive scan ----------------
__global__ void pad_scan_kernel(const int* __restrict__ cnt, int* __restrict__ cntpad,
                                int* __restrict__ offs, int* __restrict__ perm, float* __restrict__ pw)
{
  if (threadIdx.x == 0) {
    int o = 0;
    for (int e = 0; e < NE; e++) {
      int c  = cnt[e];
      int cp = (c + BM - 1) / BM * BM;
      cntpad[e] = cp;
      offs[e]   = o;
      o += cp;
    }
    offs[NE] = o;
  }
  for (int e = 0; e < NE; e++) {
    int c  = cnt[e];
    int cp = (c + BM - 1) / BM * BM;
    for (int i = c + threadIdx.x; i < cp; i += blockDim.x) {
      perm[e * T_TOK + i] = 0;
      pw[e * T_TOK + i]   = 0.f;
    }
  }
}

// ======== v3 GEMM: LDS double-buffer + 2-deep register prefetch + raw barrier ========
// LDS layout: [k-chunk g=0..3][row 0..127] of 16B chunks, pitch CH=132 -> conflict-free b128.
template<int PHASE, int KTOT, int NCOLS, int KSPLIT>
__global__ __launch_bounds__(256, 3) void moe_gemm3(
    const unsigned short* __restrict__ Asrc,
    const unsigned short* __restrict__ Bt,     // [E][NCOLS][KTOT] bf16
    const float* __restrict__ bias,
    const int* __restrict__ cntpad, const int* __restrict__ offs,
    const int* __restrict__ perm, const float* __restrict__ pw,
    unsigned short* __restrict__ Hout, float* __restrict__ out)
{
  const int e  = blockIdx.z;
  const int mt = blockIdx.y;
  const int nt = blockIdx.x / KSPLIT;
  const int ks = blockIdx.x % KSPLIT;
  const int cp = cntpad[e];
  if (mt * BM >= cp) return;
  const int tid = threadIdx.x;
  const int oe  = offs[e];

  __shared__ ushort8 AsL[2 * 4 * CH];
  __shared__ ushort8 BsL[2 * 4 * CH];
  ushort8* As0 = AsL;            ushort8* As1 = AsL + 4 * CH;
  ushort8* Bs0 = BsL;            ushort8* Bs1 = BsL + 4 * CH;

  // staging: thread = (row am, half c); holds 16 consecutive k = chunks g0, g0+1
  const int am = tid >> 1;
  const int c  = tid & 1;
  const int g0 = 2 * c;
  size_t arow;
  if (PHASE == 1) {
    int token = perm[e * T_TOK + mt * BM + am];
    arow = (size_t)token * KTOT;
  } else {
    arow = (size_t)(oe + mt * BM + am) * (size_t)KTOT;
  }
  const int kbase0 = ks * (KTOT / KSPLIT);
  const unsigned short* Ap = Asrc + arow + kbase0 + c * 16;
  const unsigned short* Bp = Bt + ((size_t)e * NCOLS + (size_t)nt * BN + am) * KTOT + kbase0 + c * 16;
  const int KITERS = (KTOT / KSPLIT) / BK;   // 32 for both phases

  const int wid  = tid >> 6;
  const int lane = tid & 63;
  const int wm   = (wid & 1) * 64;
  const int wn   = (wid >> 1) * 64;
  const int fA   = (lane >> 4) * CH + wm + (lane & 15);   // frag base (16B units)
  const int fB   = (lane >> 4) * CH + wn + (lane & 15);

  f32x4 acc[4][4];
#pragma unroll
  for (int i = 0; i < 4; i++)
#pragma unroll
    for (int j = 0; j < 4; j++) acc[i][j] = (f32x4){0.f, 0.f, 0.f, 0.f};

#define LOADT(d0, d1, d2, d3, kb) do { \
    d0 = *(const uint4*)(Ap + (kb));     d1 = *(const uint4*)(Ap + (kb) + 8); \
    d2 = *(const uint4*)(Bp + (kb));     d3 = *(const uint4*)(Bp + (kb) + 8); } while (0)
#define STAGE(ab, bb, r0, r1, r2, r3) do { \
    *(uint4*)&ab[g0 * CH + am] = r0; *(uint4*)&ab[(g0 + 1) * CH + am] = r1; \
    *(uint4*)&bb[g0 * CH + am] = r2; *(uint4*)&bb[(g0 + 1) * CH + am] = r3; } while (0)
#define COMPUTE(ab, bb) do { \
    bf16x8 af[4], bfv[4]; \
    _Pragma("unroll") for (int i = 0; i < 4; i++) af[i]  = *(const bf16x8*)&ab[fA + i * 16]; \
    _Pragma("unroll") for (int j = 0; j < 4; j++) bfv[j] = *(const bf16x8*)&bb[fB + j * 16]; \
    _Pragma("unroll") for (int i = 0; i < 4; i++) \
      _Pragma("unroll") for (int j = 0; j < 4; j++) \
        acc[i][j] = __builtin_amdgcn_mfma_f32_16x16x32_bf16(af[i], bfv[j], acc[i][j], 0, 0, 0); \
  } while (0)

  uint4 a0, a1, a2, a3;   // prefetch set A (even tiles)
  uint4 b0, b1, b2, b3;   // prefetch set B (odd tiles)

  // prologue: tile0 -> LDS buf0; tile1 in regs; tile2 loads issued inside first loop iter
  LOADT(a0, a1, a2, a3, 0);
  STAGE(As0, Bs0, a0, a1, a2, a3);
  LOADT(b0, b1, b2, b3, BK);
  wg_barrier();

  int kt = 0;
  for (; kt + 2 < KITERS; kt += 2) {
    // tile kt from buf0; stage tile kt+1; prefetch tile kt+2
    {
      STAGE(As1, Bs1, b0, b1, b2, b3);
      LOADT(a0, a1, a2, a3, (kt + 2) * BK);
      COMPUTE(As0, Bs0);
      wg_barrier();
    }
    // tile kt+1 from buf1; stage tile kt+2; prefetch tile kt+3
    {
      STAGE(As0, Bs0, a0, a1, a2, a3);
      LOADT(b0, b1, b2, b3, (kt + 3) * BK);
      COMPUTE(As1, Bs1);
      wg_barrier();
    }
  }
  // tail: buf0 = tile KITERS-2, regs b* = tile KITERS-1
  STAGE(As1, Bs1, b0, b1, b2, b3);
  COMPUTE(As0, Bs0);
  wg_barrier();
  COMPUTE(As1, Bs1);

#undef LOADT
#undef STAGE
#undef COMPUTE

  // epilogue: C/D layout col=lane&15, row=(lane>>4)*4+reg
  const int crow = (lane >> 4) * 4;
  const int ccol = lane & 15;
#pragma unroll
  for (int j = 0; j < 4; j++) {
    const int gn = nt * BN + wn + j * 16 + ccol;
    const float bv = bias[e * NCOLS + gn];
#pragma unroll
    for (int i = 0; i < 4; i++) {
#pragma unroll
      for (int r = 0; r < 4; r++) {
        const int lm = wm + i * 16 + crow + r;
        float v = acc[i][j][r];
        if (PHASE == 1) {
          v += bv;
          v = v > 0.f ? v : 0.f;
          Hout[(size_t)(oe + mt * BM + lm) * NCOLS + gn] = f2bf(v);
        } else {
          if (ks == 0) v += bv;
          const int li    = e * T_TOK + mt * BM + lm;
          const int token = perm[li];
          const float w   = pw[li];
          atomicAdd(&out[(size_t)token * NCOLS + gn], w * v);
        }
      }
    }
  }
}

extern "C" void kernel_launch(void* const* d_in, const int* in_sizes, int n_in,
                              void* d_out, int out_size, void* d_ws, size_t ws_size,
                              hipStream_t stream) {
  const float* x  = (const float*)d_in[0];
  const float* wg = (const float*)d_in[1];
  const float* bg = (const float*)d_in[2];
  const float* w1 = (const float*)d_in[3];
  const float* b1 = (const float*)d_in[4];
  const float* w2 = (const float*)d_in[5];
  const float* b2 = (const float*)d_in[6];
  float* out = (float*)d_out;

  // ---- workspace layout (r2-verified: ws_size >= 172 MB) ----
  const size_t XB_BYTES   = (size_t)T_TOK * DM * 2;
  const size_t PERM_BYTES = (size_t)NE * T_TOK * 4;
  const size_t PW_BYTES   = (size_t)NE * T_TOK * 4;
  const size_t H_BYTES    = (size_t)(2 * T_TOK + NE * BM) * DF * 2;
  const size_t W1T_BYTES  = (size_t)NE * DF * DM * 2;

  char* wsp = (char*)d_ws;
  size_t off = 0;
  unsigned short* xb = (unsigned short*)(wsp + off); off += XB_BYTES;
  int*   cnt    = (int*)(wsp + off); off += 256;
  int*   cntpad = cnt + 8;
  int*   offs   = cnt + 16;
  int*   perm   = (int*)(wsp + off);   off += PERM_BYTES;
  float* pwt    = (float*)(wsp + off); off += PW_BYTES;
  unsigned short* H   = (unsigned short*)(wsp + off); off += H_BYTES;
  unsigned short* w1t = (unsigned short*)(wsp + off); off += W1T_BYTES;
  unsigned short* w2t = (unsigned short*)(wsp + off);

  hipMemsetAsync(cnt, 0, 256, stream);
  hipMemsetAsync(d_out, 0, (size_t)T_TOK * DM * 4, stream);

  convert_x_kernel<<<(T_TOK * DM / 8) / 256, 256, 0, stream>>>(x, xb);
  gating_kernel<<<T_TOK / 4, 256, 0, stream>>>(x, wg, bg, cnt, perm, pwt);
  pad_scan_kernel<<<1, 256, 0, stream>>>(cnt, cntpad, offs, perm, pwt);

  transpose_convert<DM, DF><<<dim3(DF / 128, DM / 32, NE), 256, 0, stream>>>(w1, w1t);
  transpose_convert<DF, DM><<<dim3(DM / 128, DF / 32, NE), 256, 0, stream>>>(w2, w2t);

  moe_gemm3<1, DM, DF, 1><<<dim3(DF / BN, T_TOK / BM, NE), 256, 0, stream>>>(
      xb, w1t, b1, cntpad, offs, perm, pwt, H, nullptr);
  moe_gemm3<2, DF, DM, 4><<<dim3((DM / BN) * 4, T_TOK / BM, NE), 256, 0, stream>>>(
      H, w2t, b2, cntpad, offs, perm, pwt, nullptr, out);
}

// Round 4
// 721.360 us; speedup vs baseline: 1.0278x; 1.0278x over previous
//
#include <hip/hip_runtime.h>
#include <hip/hip_bf16.h>
#include <math.h>

#define T_TOK 2048
#define DM    1024
#define DF    4096
#define NE    8
#define BM    128
#define BN    128
#define BK    32          // k per tile (bf16) = 64 B per row

typedef __attribute__((ext_vector_type(8))) short          bf16x8;
typedef __attribute__((ext_vector_type(8))) unsigned short ushort8;
typedef __attribute__((ext_vector_type(4))) float          f32x4;

__device__ __forceinline__ unsigned short f2bf(float f) {
  unsigned u = __builtin_bit_cast(unsigned, f);
  unsigned r = u + 0x7fffu + ((u >> 16) & 1u);   // RNE
  return (unsigned short)(r >> 16);
}

// async global->LDS, 16B per lane; LDS dest = wave-uniform base + lane*16
__device__ __forceinline__ void load_lds16(const void* g, void* l) {
  __builtin_amdgcn_global_load_lds(
      (const __attribute__((address_space(1))) void*)g,
      (__attribute__((address_space(3))) void*)l, 16, 0, 0);
}

// barrier that does NOT drain the vmem queue: wait only until <=N loads outstanding
#define BAR(vm) asm volatile("s_waitcnt vmcnt(" #vm ") lgkmcnt(0)\n\ts_barrier" ::: "memory")

// ---------------- x f32 -> bf16 ----------------
__global__ void convert_x_kernel(const float* __restrict__ x, unsigned short* __restrict__ xb) {
  int i = blockIdx.x * blockDim.x + threadIdx.x;
  const float* src = x + (size_t)i * 8;
  float4 a = *(const float4*)(src);
  float4 b = *(const float4*)(src + 4);
  ushort8 v;
  v[0] = f2bf(a.x); v[1] = f2bf(a.y); v[2] = f2bf(a.z); v[3] = f2bf(a.w);
  v[4] = f2bf(b.x); v[5] = f2bf(b.y); v[6] = f2bf(b.z); v[7] = f2bf(b.w);
  *(ushort8*)(xb + (size_t)i * 8) = v;
}

// ---------------- weight convert + transpose: W[E][K][N] f32 -> Wt[E][N][K] bf16 ----------------
template<int K, int N>
__global__ __launch_bounds__(256) void transpose_convert(
    const float* __restrict__ W, unsigned short* __restrict__ Wt)
{
  const int e  = blockIdx.z;
  const int k0 = blockIdx.y * 32;
  const int n0 = blockIdx.x * 128;
  const float* Wp = W + (size_t)e * K * N;
  unsigned short* Wo = Wt + (size_t)e * N * K;
  __shared__ float Ls[32][132];
  const int tid = threadIdx.x;
  {
    const int kl = tid >> 5;
    const int nl = (tid & 31) * 4;
#pragma unroll
    for (int p = 0; p < 4; p++) {
      const int k = kl + p * 8;
      float4 v = *(const float4*)(Wp + (size_t)(k0 + k) * N + n0 + nl);
      *(float4*)&Ls[k][nl] = v;
    }
  }
  __syncthreads();
  {
    const int n  = tid & 127;
    const int c0 = tid >> 7;
#pragma unroll
    for (int p = 0; p < 2; p++) {
      const int c = c0 + p * 2;
      ushort8 o;
#pragma unroll
      for (int j = 0; j < 8; j++) o[j] = f2bf(Ls[c * 8 + j][n]);
      *(ushort8*)(Wo + (size_t)(n0 + n) * K + k0 + c * 8) = o;
    }
  }
}

// ---------------- gating: one wave per token ----------------
__global__ __launch_bounds__(256) void gating_kernel(
    const float* __restrict__ x, const float* __restrict__ wg, const float* __restrict__ bg,
    int* __restrict__ cnt, int* __restrict__ perm, float* __restrict__ pw)
{
  int wid  = (blockIdx.x * blockDim.x + threadIdx.x) >> 6;
  int lane = threadIdx.x & 63;
  if (wid >= T_TOK) return;
  const float* xr = x + (size_t)wid * DM;

  float acc[NE];
#pragma unroll
  for (int e = 0; e < NE; e++) acc[e] = 0.f;
  for (int d = lane; d < DM; d += 64) {
    float xv = xr[d];
    const float* wr = wg + (size_t)d * NE;
#pragma unroll
    for (int e = 0; e < NE; e++) acc[e] += xv * wr[e];
  }
#pragma unroll
  for (int off = 32; off > 0; off >>= 1) {
#pragma unroll
    for (int e = 0; e < NE; e++) acc[e] += __shfl_xor(acc[e], off, 64);
  }
  if (lane == 0) {
    float v[NE];
#pragma unroll
    for (int e = 0; e < NE; e++) v[e] = acc[e] + bg[e];
    int i0 = 0; float v0 = v[0];
#pragma unroll
    for (int e = 1; e < NE; e++) { if (v[e] > v0) { v0 = v[e]; i0 = e; } }
    int i1 = -1; float v1 = -INFINITY;
#pragma unroll
    for (int e = 0; e < NE; e++) { if (e != i0 && v[e] > v1) { v1 = v[e]; i1 = e; } }
    float e1 = expf(v1 - v0);
    float s  = 1.f + e1;
    float w0 = 1.f / s, w1 = e1 / s;
    int p0 = atomicAdd(&cnt[i0], 1);
    perm[i0 * T_TOK + p0] = wid; pw[i0 * T_TOK + p0] = w0;
    int p1 = atomicAdd(&cnt[i1], 1);
    perm[i1 * T_TOK + p1] = wid; pw[i1 * T_TOK + p1] = w1;
  }
}

// ---------------- pad lists to BM multiple + exclusive scan ----------------
__global__ void pad_scan_kernel(const int* __restrict__ cnt, int* __restrict__ cntpad,
                                int* __restrict__ offs, int* __restrict__ perm, float* __restrict__ pw)
{
  if (threadIdx.x == 0) {
    int o = 0;
    for (int e = 0; e < NE; e++) {
      int c  = cnt[e];
      int cp = (c + BM - 1) / BM * BM;
      cntpad[e] = cp;
      offs[e]   = o;
      o += cp;
    }
    offs[NE] = o;
  }
  for (int e = 0; e < NE; e++) {
    int c  = cnt[e];
    int cp = (c + BM - 1) / BM * BM;
    for (int i = c + threadIdx.x; i < cp; i += blockDim.x) {
      perm[e * T_TOK + i] = 0;
      pw[e * T_TOK + i]   = 0.f;
    }
  }
}

// ======== v4 GEMM: global_load_lds, 4 LDS buffers, 3 tiles in flight, vmcnt(N) barriers ========
// LDS tile layout: [row 0..127][chunk 0..3] of 16B, row = 64B; chunk XOR-swizzled by (row>>1)&3
// so ds_read_b128 frag reads are 2-way max (free) and staging is lane*16-contiguous.
template<int PHASE, int KTOT, int NCOLS, int KSPLIT>
__global__ __launch_bounds__(256, 2) void moe_gemm4(
    const unsigned short* __restrict__ Asrc,
    const unsigned short* __restrict__ Bt,     // [E][NCOLS][KTOT] bf16
    const float* __restrict__ bias,
    const int* __restrict__ cntpad, const int* __restrict__ offs,
    const int* __restrict__ perm, const float* __restrict__ pw,
    unsigned short* __restrict__ Hout, float* __restrict__ out)
{
  const int e  = blockIdx.z;
  const int mt = blockIdx.y;
  const int nt = blockIdx.x / KSPLIT;
  const int ks = blockIdx.x % KSPLIT;
  const int cp = cntpad[e];
  if (mt * BM >= cp) return;
  const int tid = threadIdx.x;
  const int oe  = offs[e];

  __shared__ __align__(16) unsigned short As[4 * BM * BK];   // 4 bufs x 8 KB
  __shared__ __align__(16) unsigned short Bs[4 * BN * BK];

  const int wid  = tid >> 6;
  const int lane = tid & 63;
  const int kbase0 = ks * (KTOT / KSPLIT);
  const int KITERS = (KTOT / KSPLIT) / BK;   // 32 in both phases

  // --- staging setup: wave w covers rows [w*32, w*32+32), 2 issues of 16 rows for A and B ---
  const unsigned short* agp[2];
  const unsigned short* bgp[2];
  int aofs[2];   // wave-uniform LDS base (ushort index) per issue
#pragma unroll
  for (int i = 0; i < 2; i++) {
    const int r  = wid * 32 + i * 16 + (lane >> 2);
    const int gc = (lane & 3) ^ ((r >> 1) & 3);
    size_t arow;
    if (PHASE == 1) {
      int token = perm[e * T_TOK + mt * BM + r];
      arow = (size_t)token * KTOT;
    } else {
      arow = (size_t)(oe + mt * BM + r) * (size_t)KTOT;
    }
    agp[i]  = Asrc + arow + kbase0 + gc * 8;
    bgp[i]  = Bt + ((size_t)e * NCOLS + (size_t)nt * BN + r) * KTOT + kbase0 + gc * 8;
    aofs[i] = (wid * 32 + i * 16) * BK;      // 16 rows * 32 ushorts
  }

  // --- fragment read offsets (ushort index within a buffer), XOR-swizzled ---
  const int wm = (wid & 1) * 64;
  const int wn = (wid >> 1) * 64;
  int faOff[4], fbOff[4];
#pragma unroll
  for (int i = 0; i < 4; i++) {
    const int ra = wm + i * 16 + (lane & 15);
    faOff[i] = ra * BK + (((lane >> 4) ^ ((ra >> 1) & 3)) * 8);
    const int rb = wn + i * 16 + (lane & 15);
    fbOff[i] = rb * BK + (((lane >> 4) ^ ((rb >> 1) & 3)) * 8);
  }

  f32x4 acc[4][4];
#pragma unroll
  for (int i = 0; i < 4; i++)
#pragma unroll
    for (int j = 0; j < 4; j++) acc[i][j] = (f32x4){0.f, 0.f, 0.f, 0.f};

#define ISSUE(kt) do { const int _bo = ((kt) & 3) * (BM * BK); \
    load_lds16(agp[0] + (size_t)(kt) * BK, &As[_bo + aofs[0]]); \
    load_lds16(agp[1] + (size_t)(kt) * BK, &As[_bo + aofs[1]]); \
    load_lds16(bgp[0] + (size_t)(kt) * BK, &Bs[_bo + aofs[0]]); \
    load_lds16(bgp[1] + (size_t)(kt) * BK, &Bs[_bo + aofs[1]]); } while (0)

#define COMPUTE(kt) do { const int _bo = ((kt) & 3) * (BM * BK); \
    bf16x8 af[4], bfv[4]; \
    _Pragma("unroll") for (int i = 0; i < 4; i++) af[i]  = *(const bf16x8*)&As[_bo + faOff[i]]; \
    _Pragma("unroll") for (int j = 0; j < 4; j++) bfv[j] = *(const bf16x8*)&Bs[_bo + fbOff[j]]; \
    _Pragma("unroll") for (int i = 0; i < 4; i++) \
      _Pragma("unroll") for (int j = 0; j < 4; j++) \
        acc[i][j] = __builtin_amdgcn_mfma_f32_16x16x32_bf16(af[i], bfv[j], acc[i][j], 0, 0, 0); \
  } while (0)

  // prologue: 3 tiles in flight (12 outstanding per wave, 4 issues per tile)
  ISSUE(0); ISSUE(1); ISSUE(2);

  for (int kt = 0; kt < KITERS - 4; kt += 4) {
    BAR(8); ISSUE(kt + 3); COMPUTE(kt + 0);
    BAR(8); ISSUE(kt + 4); COMPUTE(kt + 1);
    BAR(8); ISSUE(kt + 5); COMPUTE(kt + 2);
    BAR(8); ISSUE(kt + 6); COMPUTE(kt + 3);
  }
  // tail: tiles KITERS-4 .. KITERS-1 (last issue = KITERS-1 in first slot)
  BAR(8); ISSUE(KITERS - 1); COMPUTE(KITERS - 4);
  BAR(8);                    COMPUTE(KITERS - 3);
  BAR(4);                    COMPUTE(KITERS - 2);
  BAR(0);                    COMPUTE(KITERS - 1);

#undef ISSUE
#undef COMPUTE

  // epilogue: C/D layout col=lane&15, row=(lane>>4)*4+reg
  const int crow = (lane >> 4) * 4;
  const int ccol = lane & 15;
#pragma unroll
  for (int j = 0; j < 4; j++) {
    const int gn = nt * BN + wn + j * 16 + ccol;
    const float bv = bias[e * NCOLS + gn];
#pragma unroll
    for (int i = 0; i < 4; i++) {
#pragma unroll
      for (int r = 0; r < 4; r++) {
        const int lm = wm + i * 16 + crow + r;
        float v = acc[i][j][r];
        if (PHASE == 1) {
          v += bv;
          v = v > 0.f ? v : 0.f;
          Hout[(size_t)(oe + mt * BM + lm) * NCOLS + gn] = f2bf(v);
        } else {
          if (ks == 0) v += bv;
          const int li    = e * T_TOK + mt * BM + lm;
          const int token = perm[li];
          const float w   = pw[li];
          atomicAdd(&out[(size_t)token * NCOLS + gn], w * v);
        }
      }
    }
  }
}

extern "C" void kernel_launch(void* const* d_in, const int* in_sizes, int n_in,
                              void* d_out, int out_size, void* d_ws, size_t ws_size,
                              hipStream_t stream) {
  const float* x  = (const float*)d_in[0];
  const float* wg = (const float*)d_in[1];
  const float* bg = (const float*)d_in[2];
  const float* w1 = (const float*)d_in[3];
  const float* b1 = (const float*)d_in[4];
  const float* w2 = (const float*)d_in[5];
  const float* b2 = (const float*)d_in[6];
  float* out = (float*)d_out;

  const size_t XB_BYTES   = (size_t)T_TOK * DM * 2;
  const size_t PERM_BYTES = (size_t)NE * T_TOK * 4;
  const size_t PW_BYTES   = (size_t)NE * T_TOK * 4;
  const size_t H_BYTES    = (size_t)(2 * T_TOK + NE * BM) * DF * 2;
  const size_t W1T_BYTES  = (size_t)NE * DF * DM * 2;

  char* wsp = (char*)d_ws;
  size_t off = 0;
  unsigned short* xb = (unsigned short*)(wsp + off); off += XB_BYTES;
  int*   cnt    = (int*)(wsp + off); off += 256;
  int*   cntpad = cnt + 8;
  int*   offs   = cnt + 16;
  int*   perm   = (int*)(wsp + off);   off += PERM_BYTES;
  float* pwt    = (float*)(wsp + off); off += PW_BYTES;
  unsigned short* H   = (unsigned short*)(wsp + off); off += H_BYTES;
  unsigned short* w1t = (unsigned short*)(wsp + off); off += W1T_BYTES;
  unsigned short* w2t = (unsigned short*)(wsp + off);

  hipMemsetAsync(cnt, 0, 256, stream);
  hipMemsetAsync(d_out, 0, (size_t)T_TOK * DM * 4, stream);

  convert_x_kernel<<<(T_TOK * DM / 8) / 256, 256, 0, stream>>>(x, xb);
  gating_kernel<<<T_TOK / 4, 256, 0, stream>>>(x, wg, bg, cnt, perm, pwt);
  pad_scan_kernel<<<1, 256, 0, stream>>>(cnt, cntpad, offs, perm, pwt);

  transpose_convert<DM, DF><<<dim3(DF / 128, DM / 32, NE), 256, 0, stream>>>(w1, w1t);
  transpose_convert<DF, DM><<<dim3(DM / 128, DF / 32, NE), 256, 0, stream>>>(w2, w2t);

  moe_gemm4<1, DM, DF, 1><<<dim3(DF / BN, T_TOK / BM, NE), 256, 0, stream>>>(
      xb, w1t, b1, cntpad, offs, perm, pwt, H, nullptr);
  moe_gemm4<2, DF, DM, 4><<<dim3((DM / BN) * 4, T_TOK / BM, NE), 256, 0, stream>>>(
      H, w2t, b2, cntpad, offs, perm, pwt, nullptr, out);
}